// Round 3
// baseline (170015.796 us; speedup 1.0000x reference)
//
#include <hip/hip_runtime.h>
#include <hip/hip_bf16.h>
#include <cstddef>
#include <cstdint>

// ---------------------------------------------------------------------------
// RecurrentEncoderDecoder (B=128, T=512, H=512, HOR=64, M=1, Q=5, DFF=7)
// Round 3: round-2 run aborted (GPU memory fault suspected: workspace layout
// needed 261.5 MiB; ws_size likely 256 MiB). Fix: ys1 record stored as bf16
// (consumed only by layer-1 input GEMM; one-shot rounding, no recurrent
// accumulation). Layer-0 recurrence kept fp32 via small h0state parity
// buffers. Total workspace now ~134.5 MiB.
//
// All sequences transposed [k][b] (b fastest) so lane=b is coalesced.
// Cell kernel: grid = ndirs*128 blocks x 256 threads; block = (dir, b-half,
// 8 h rows); thread = (b, 2 h rows) -> 8 fp32 accumulators (4 gates x 2 h).
// h staged via LDS 128 rows at a time; weights via wave-uniform scalar loads.
//
// Workspace layout:
//   Xt      [512][8][128]                f32   524288
//   h0state [2 par][2 dir][512][128]     f32   262144
//   h1T     [2 par][2 dir][512][128]     f32   262144
//   c0buf   [2 dir][512][128]            f32   131072
//   c1buf   [2 dir][512][128]            f32   131072
//   hdec    [2 par][2 layer][512][128]   f32   262144
//   cdec    [2 layer][512][128]          f32   131072
//   xdecT   [8][128]                     f32     1024
//   ys1b    [512][1024][128]             bf16  67108864   (128 MiB)
// ---------------------------------------------------------------------------

__device__ __forceinline__ float sigm_(float x) { return 1.0f / (1.0f + __expf(-x)); }
__device__ __forceinline__ float ldf_(const float* p) { return *p; }
__device__ __forceinline__ float ldf_(const __hip_bfloat16* p) { return __bfloat162float(*p); }

template<int LEN, typename T>
__device__ __forceinline__ void seg_accum(
    const T* __restrict__ Xs,       // [LEN][128] transposed segment
    const float* __restrict__ W,    // [2048][LEN] row-major weights
    int h0, int colbase, int lane, int warp,
    float (&acc)[2][4], float (*lds)[64])
{
  const float* __restrict__ Wr[2][4];
#pragma unroll
  for (int hh = 0; hh < 2; ++hh)
#pragma unroll
    for (int g = 0; g < 4; ++g)
      Wr[hh][g] = W + (size_t)(g * 512 + h0 + hh) * LEN;

  if constexpr (LEN <= 128) {
    __syncthreads();
#pragma unroll
    for (int j = 0; j < (LEN + 3) / 4; ++j) {
      int kl = j * 4 + warp;
      if (kl < LEN) lds[kl][lane] = ldf_(&Xs[(size_t)kl * 128 + colbase + lane]);
    }
    __syncthreads();
#pragma unroll
    for (int k = 0; k < LEN; ++k) {
      float hv = lds[k][lane];
#pragma unroll
      for (int hh = 0; hh < 2; ++hh)
#pragma unroll
        for (int g = 0; g < 4; ++g)
          acc[hh][g] = fmaf(hv, Wr[hh][g][k], acc[hh][g]);
    }
  } else {
#pragma unroll 1
    for (int k0 = 0; k0 < LEN; k0 += 128) {
      __syncthreads();
#pragma unroll
      for (int j = 0; j < 32; ++j) {
        int kl = j * 4 + warp;
        lds[kl][lane] = ldf_(&Xs[(size_t)(k0 + kl) * 128 + colbase + lane]);
      }
      __syncthreads();
#pragma unroll 2
      for (int k = 0; k < 128; k += 2) {
        float hv0 = lds[k][lane];
        float hv1 = lds[k + 1][lane];
#pragma unroll
        for (int hh = 0; hh < 2; ++hh)
#pragma unroll
          for (int g = 0; g < 4; ++g) {
            acc[hh][g] = fmaf(hv0, Wr[hh][g][k0 + k], acc[hh][g]);
            acc[hh][g] = fmaf(hv1, Wr[hh][g][k0 + k + 1], acc[hh][g]);
          }
      }
    }
  }
}

// One LSTM cell time-step for up to 2 independent directions.
// grid = ndirs*128 blocks (dir = blockIdx.x>=128), 256 threads.
// TA = element type of the x-input segment; WBF: also record h as bf16.
template<int LENA, bool FIRST, typename TA, bool WBF>
__global__ __launch_bounds__(256) void k_cell(
    const TA* __restrict__ xa0, const float* __restrict__ xb0,
    const float* __restrict__ wa0, const float* __restrict__ wb0,
    const float* __restrict__ bias0,
    const float* __restrict__ cin0, float* __restrict__ cout0,
    float* __restrict__ hout0, __hip_bfloat16* __restrict__ hbf0,
    const TA* __restrict__ xa1, const float* __restrict__ xb1,
    const float* __restrict__ wa1, const float* __restrict__ wb1,
    const float* __restrict__ bias1,
    const float* __restrict__ cin1, float* __restrict__ cout1,
    float* __restrict__ hout1, __hip_bfloat16* __restrict__ hbf1)
{
  __shared__ float lds[128][64];
  const bool d1 = (blockIdx.x >= 128);
  const TA*    __restrict__ xa   = d1 ? xa1   : xa0;
  const float* __restrict__ xb   = d1 ? xb1   : xb0;
  const float* __restrict__ wa   = d1 ? wa1   : wa0;
  const float* __restrict__ wb   = d1 ? wb1   : wb0;
  const float* __restrict__ bias = d1 ? bias1 : bias0;
  const float* __restrict__ cin  = d1 ? cin1  : cin0;
  float* __restrict__ cout = d1 ? cout1 : cout0;
  float* __restrict__ hout = d1 ? hout1 : hout0;
  __hip_bfloat16* __restrict__ hbf = d1 ? hbf1 : hbf0;

  const int bid  = blockIdx.x & 127;
  const int tid  = threadIdx.x;
  const int lane = tid & 63;
  const int warp = tid >> 6;
  const int half = bid & 1;
  const int colbase = half << 6;
  const int h0 = __builtin_amdgcn_readfirstlane(((bid >> 1) << 3) + (warp << 1));
  const int b  = colbase + lane;

  float acc[2][4];
#pragma unroll
  for (int hh = 0; hh < 2; ++hh)
#pragma unroll
    for (int g = 0; g < 4; ++g)
      acc[hh][g] = bias[g * 512 + h0 + hh];

  seg_accum<LENA, TA>(xa, wa, h0, colbase, lane, warp, acc, lds);
  if constexpr (!FIRST)
    seg_accum<512, float>(xb, wb, h0, colbase, lane, warp, acc, lds);

#pragma unroll
  for (int hh = 0; hh < 2; ++hh) {
    int h = h0 + hh;
    float cp = FIRST ? 0.0f : cin[h * 128 + b];
    float gi = acc[hh][0], gf = acc[hh][1], gg = acc[hh][2], go = acc[hh][3];
    float c  = sigm_(gf) * cp + sigm_(gi) * tanhf(gg);
    float hv = sigm_(go) * tanhf(c);
    cout[h * 128 + b] = c;
    hout[h * 128 + b] = hv;
    if constexpr (WBF) hbf[h * 128 + b] = __float2bfloat16(hv);
  }
}

// Transpose X -> Xt [t][j][128]; build xdecT for decoder t=0.
__global__ __launch_bounds__(256) void k_pre(
    const float* __restrict__ X, const float* __restrict__ fut,
    float* __restrict__ Xt, float* __restrict__ xdecT)
{
  int t = blockIdx.x;
  int tid = threadIdx.x;
  for (int i = tid; i < 1024; i += 256) {
    int j = i >> 7, b = i & 127;
    Xt[(size_t)t * 1024 + j * 128 + b] = X[(size_t)b * 4096 + t * 8 + j];
  }
  if (t == 0 && tid < 128) {
    int b = tid;
    xdecT[b] = X[(size_t)b * 4096 + 511 * 8 + 0];
#pragma unroll
    for (int j = 0; j < 7; ++j)
      xdecT[(1 + j) * 128 + b] = fut[(size_t)b * 448 + j];
  }
}

// h_m / c_m = elu([hf0,hb0,hf1,hb1] @ w_bidi.T + b_bidi) -> decoder initial
// states. grid = 1024 blocks x 256 threads; wave = (sel, n, half).
__global__ __launch_bounds__(256) void k_mix(
    const float* __restrict__ h0f, const float* __restrict__ h0b,
    const float* __restrict__ h1f, const float* __restrict__ h1b,
    const float* __restrict__ c0f, const float* __restrict__ c0bb,
    const float* __restrict__ c1f, const float* __restrict__ c1bb,
    const float* __restrict__ w, const float* __restrict__ bias,
    float* __restrict__ h_dst, float* __restrict__ c_dst)
{
  int wgl  = blockIdx.x * 4 + (threadIdx.x >> 6);
  int lane = threadIdx.x & 63;
  int sel  = __builtin_amdgcn_readfirstlane(wgl >> 11);
  int rem  = wgl & 2047;
  int n    = __builtin_amdgcn_readfirstlane(rem >> 1);
  int half = rem & 1;
  int b    = (half << 6) + lane;
  const float* __restrict__ A0 = sel ? c0f  : h0f;
  const float* __restrict__ A1 = sel ? c0bb : h0b;
  const float* __restrict__ A2 = sel ? c1f  : h1f;
  const float* __restrict__ A3 = sel ? c1bb : h1b;
  const float* __restrict__ Wn = w + (size_t)n * 2048;
  float acc = bias[n];
#pragma unroll 8
  for (int k = 0; k < 512; ++k) acc = fmaf(A0[k * 128 + b], Wn[k], acc);
#pragma unroll 8
  for (int k = 0; k < 512; ++k) acc = fmaf(A1[k * 128 + b], Wn[512 + k], acc);
#pragma unroll 8
  for (int k = 0; k < 512; ++k) acc = fmaf(A2[k * 128 + b], Wn[1024 + k], acc);
#pragma unroll 8
  for (int k = 0; k < 512; ++k) acc = fmaf(A3[k * 128 + b], Wn[1536 + k], acc);
  float v = acc > 0.0f ? acc : (__expf(acc) - 1.0f);
  float* dst = sel ? c_dst : h_dst;
  dst[n * 128 + b] = v;
}

// y = h1 @ w_out.T + b_out -> out[:,t,:,:]; feed back y[:,0] and fut[t+1]
// into xdecT. grid = 11 blocks x 256.
__global__ __launch_bounds__(256) void k_dec_out(
    const float* __restrict__ h1, const float* __restrict__ w_out,
    const float* __restrict__ b_out, const float* __restrict__ fut,
    float* __restrict__ out, float* __restrict__ xdecT, int t)
{
  __shared__ float red[4][64];
  int bid = blockIdx.x;
  int tid = threadIdx.x;
  if (bid == 10) {
    if (tid < 128 && t + 1 < 64) {
      int b = tid;
#pragma unroll
      for (int j = 0; j < 7; ++j)
        xdecT[(1 + j) * 128 + b] = fut[(size_t)b * 448 + (t + 1) * 7 + j];
    }
    return;
  }
  int lane = tid & 63, warp = tid >> 6;
  int q    = __builtin_amdgcn_readfirstlane(bid >> 1);
  int half = bid & 1;
  int b    = half * 64 + lane;
  const float* __restrict__ Wq = w_out + q * 512 + warp * 128;
  const float* __restrict__ Hh = h1 + (size_t)warp * 128 * 128;
  float acc = 0.0f;
#pragma unroll 8
  for (int k = 0; k < 128; ++k) acc = fmaf(Hh[k * 128 + b], Wq[k], acc);
  red[warp][lane] = acc;
  __syncthreads();
  if (warp == 0) {
    float s = red[0][lane] + red[1][lane] + red[2][lane] + red[3][lane] + b_out[q];
    out[(size_t)b * 320 + t * 5 + q] = s;
    if (q == 0 && t + 1 < 64) xdecT[b] = s;
  }
}

extern "C" void kernel_launch(void* const* d_in, const int* in_sizes, int n_in,
                              void* d_out, int out_size, void* d_ws, size_t ws_size,
                              hipStream_t stream) {
  (void)in_sizes; (void)n_in; (void)out_size; (void)ws_size;
  const float* X      = (const float*)d_in[0];
  const float* fut    = (const float*)d_in[1];
  // d_in[2] Y_teacher, d_in[3] horizon_span: unused
  const float* e_wih0 = (const float*)d_in[4];
  const float* e_whh0 = (const float*)d_in[5];
  const float* e_b0   = (const float*)d_in[6];
  const float* e_wih1 = (const float*)d_in[7];
  const float* e_whh1 = (const float*)d_in[8];
  const float* e_b1   = (const float*)d_in[9];
  const float* d_wih0 = (const float*)d_in[10];
  const float* d_whh0 = (const float*)d_in[11];
  const float* d_b0   = (const float*)d_in[12];
  const float* d_wih1 = (const float*)d_in[13];
  const float* d_whh1 = (const float*)d_in[14];
  const float* d_b1   = (const float*)d_in[15];
  const float* w_bidi = (const float*)d_in[16];
  const float* b_bidi = (const float*)d_in[17];
  const float* w_out  = (const float*)d_in[18];
  const float* b_out  = (const float*)d_in[19];
  float* out = (float*)d_out;

  float* ws    = (float*)d_ws;
  float* Xt    = ws;                       // 524288
  float* h0s   = Xt + 524288;              // 262144  [par][dir][512][128]
  float* h1T   = h0s + 262144;             // 262144  [par][dir][512][128]
  float* c0buf = h1T + 262144;             // 131072  [dir][512][128]
  float* c1buf = c0buf + 131072;           // 131072
  float* hdec  = c1buf + 131072;           // 262144  [par][layer][512][128]
  float* cdec  = hdec + 262144;            // 131072  [layer][512][128]
  float* xdecT = cdec + 131072;            // 1024
  __hip_bfloat16* ys1b = (__hip_bfloat16*)(xdecT + 1024);  // 67108864 bf16

  k_pre<<<512, 256, 0, stream>>>(X, fut, Xt, xdecT);

  // ---- encoder layer 0: 512 steps, both directions ----
  for (int s = 0; s < 512; ++s) {
    int t = 511 - s;
    int pr = s & 1, pw = pr ^ 1;
    const float* xa0 = Xt + (size_t)s * 1024;
    const float* xb0 = h0s + (size_t)pr * 131072;
    float* ho0 = h0s + (size_t)pw * 131072;
    __hip_bfloat16* hb0 = ys1b + (size_t)s * 131072;
    const float* xa1 = Xt + (size_t)t * 1024;
    const float* xb1 = h0s + (size_t)pr * 131072 + 65536;
    float* ho1 = h0s + (size_t)pw * 131072 + 65536;
    __hip_bfloat16* hb1 = ys1b + (size_t)t * 131072 + 65536;
    if (s == 0)
      k_cell<8, true, float, true><<<256, 256, 0, stream>>>(
          xa0, xb0, e_wih0, e_whh0, e_b0, nullptr, c0buf, ho0, hb0,
          xa1, xb1, e_wih0 + 2048 * 8, e_whh0 + (size_t)2048 * 512, e_b0 + 2048,
          nullptr, c0buf + 65536, ho1, hb1);
    else
      k_cell<8, false, float, true><<<256, 256, 0, stream>>>(
          xa0, xb0, e_wih0, e_whh0, e_b0, c0buf, c0buf, ho0, hb0,
          xa1, xb1, e_wih0 + 2048 * 8, e_whh0 + (size_t)2048 * 512, e_b0 + 2048,
          c0buf + 65536, c0buf + 65536, ho1, hb1);
  }
  // final L0 states land at parity 0 (s=511: pw=0)

  // ---- encoder layer 1: 512 steps, both directions (x = ys1b[t], K=1024) ----
  for (int s = 0; s < 512; ++s) {
    int t = 511 - s;
    int pr = s & 1, pw = pr ^ 1;
    const __hip_bfloat16* xa0 = ys1b + (size_t)s * 131072;
    const float* xb0 = h1T + (size_t)pr * 131072;
    float* ho0 = h1T + (size_t)pw * 131072;
    const __hip_bfloat16* xa1 = ys1b + (size_t)t * 131072;
    const float* xb1 = h1T + (size_t)pr * 131072 + 65536;
    float* ho1 = h1T + (size_t)pw * 131072 + 65536;
    const float* wa1 = e_wih1 + (size_t)2048 * 1024;
    const float* wb1 = e_whh1 + (size_t)2048 * 512;
    if (s == 0)
      k_cell<1024, true, __hip_bfloat16, false><<<256, 256, 0, stream>>>(
          xa0, xb0, e_wih1, e_whh1, e_b1, nullptr, c1buf, ho0, nullptr,
          xa1, xb1, wa1, wb1, e_b1 + 2048, nullptr, c1buf + 65536, ho1, nullptr);
    else
      k_cell<1024, false, __hip_bfloat16, false><<<256, 256, 0, stream>>>(
          xa0, xb0, e_wih1, e_whh1, e_b1, c1buf, c1buf, ho0, nullptr,
          xa1, xb1, wa1, wb1, e_b1 + 2048, c1buf + 65536, c1buf + 65536, ho1, nullptr);
  }
  // final L1 states land at parity 0 (s=511: pw=0)

  // ---- bidi-state mixing -> decoder initial states (parity 0) ----
  k_mix<<<1024, 256, 0, stream>>>(
      h0s + 0, h0s + 65536,                  // hf0, hb0 (parity 0)
      h1T + 0, h1T + 65536,                  // hf1, hb1 (parity 0)
      c0buf, c0buf + 65536, c1buf, c1buf + 65536,
      w_bidi, b_bidi,
      hdec,                                  // parity 0: [layer][512][128]
      cdec);

  // ---- decoder: 64 autoregressive steps ----
  for (int t = 0; t < 64; ++t) {
    int pr = t & 1, pw = pr ^ 1;
    {
      const float* xa = xdecT;
      const float* xb = hdec + (size_t)pr * 131072;
      float* ho = hdec + (size_t)pw * 131072;
      k_cell<8, false, float, false><<<128, 256, 0, stream>>>(
          xa, xb, d_wih0, d_whh0, d_b0, cdec, cdec, ho, nullptr,
          xa, xb, d_wih0, d_whh0, d_b0, cdec, cdec, ho, nullptr);
    }
    {
      const float* xa = hdec + (size_t)pw * 131072;            // h0 (current)
      const float* xb = hdec + (size_t)pr * 131072 + 65536;    // h1 (prev)
      float* ho = hdec + (size_t)pw * 131072 + 65536;
      k_cell<512, false, float, false><<<128, 256, 0, stream>>>(
          xa, xb, d_wih1, d_whh1, d_b1, cdec + 65536, cdec + 65536, ho, nullptr,
          xa, xb, d_wih1, d_whh1, d_b1, cdec + 65536, cdec + 65536, ho, nullptr);
    }
    k_dec_out<<<11, 256, 0, stream>>>(hdec + (size_t)pw * 131072 + 65536,
                                      w_out, b_out, fut, out, xdecT, t);
  }
}

// Round 4
// 44562.070 us; speedup vs baseline: 3.8153x; 3.8153x over previous
//
#include <hip/hip_runtime.h>
#include <hip/hip_bf16.h>
#include <cstddef>
#include <cstdint>

// ---------------------------------------------------------------------------
// RecurrentEncoderDecoder (B=128, T=512, H=512, HOR=64, M=1, Q=5, DFF=7)
// Round 4: occupancy-fixed k-split cells (16 waves/CU) + enc-L1 input GEMM
// hoisted out of the recurrence as a bf16 MFMA GEMM over 32-step windows.
//
// Workspace (floats, total ~216.5 MiB):
//   Xt      [512][8][128]                  524288
//   h0s     [2 par][2 dir][512][128]       262144
//   h1T     [2 par][2 dir][512][128]       262144
//   c0buf   [2 dir][512][128]              131072
//   c1buf   [2 dir][512][128]              131072
//   hdec    [2 par][2 layer][512][128]     262144
//   cdec    [2 layer][512][128]            131072
//   xdecT   [8][128]                         1024
//   winbuf  [2 dir][32][2048][128]       16777216   (64 MiB, gates = W_ih1·x)
//   wihb    bf16 [2][2048][1024]          2097152 float-slots (8 MiB)
//   ys1b    bf16 [512][1024][128]        33554432 float-slots (128 MiB)
// ---------------------------------------------------------------------------

typedef __attribute__((ext_vector_type(8))) short short8;
typedef __attribute__((ext_vector_type(4))) float f32x4;

__device__ __forceinline__ float sigm_(float x) { return 1.0f / (1.0f + __expf(-x)); }

// ---------------------------------------------------------------------------
// k-split LSTM cell. Block = 1024 threads = 16 waves: warp = (kc in [0,4)) x
// (wh in [0,4)). Grid = ndirs*128: bid7 = blockIdx.x&127 -> bhalf = bid7&1,
// hgrp = bid7>>1 (64 groups x 8 h rows). Warp wh owns h rows hgrp*8+wh*2+{0,1}
// x 4 gates = 8 accs over 64 batch lanes. K: optional XLEN=8 global-direct
// rows (kc0) + NSEG segments of 512 rows staged in LDS as 2x256-row phases,
// warp kc covering 64 rows per phase. kc1..3 partials reduced via LDS (which
// aliases the stage buffer). Gate init = bias (+ gin if non-null).
// ---------------------------------------------------------------------------
template<int XLEN, int NSEG, bool FIRST, bool WBF>
__global__ __launch_bounds__(1024) void k_cellK(
    const float* __restrict__ xa0, const float* __restrict__ s1_0, const float* __restrict__ s2_0,
    const float* __restrict__ wa0, const float* __restrict__ w1_0, const float* __restrict__ w2_0,
    const float* __restrict__ bias0, const float* __restrict__ gin0,
    const float* __restrict__ cin0, float* __restrict__ cout0,
    float* __restrict__ hout0, __hip_bfloat16* __restrict__ hbf0,
    const float* __restrict__ xa1, const float* __restrict__ s1_1, const float* __restrict__ s2_1,
    const float* __restrict__ wa1, const float* __restrict__ w1_1, const float* __restrict__ w2_1,
    const float* __restrict__ bias1, const float* __restrict__ gin1,
    const float* __restrict__ cin1, float* __restrict__ cout1,
    float* __restrict__ hout1, __hip_bfloat16* __restrict__ hbf1)
{
  __shared__ float xbuf[256 * 64];   // 64 KB stage buffer; aliased for reduce

  const bool d1 = (blockIdx.x >= 128);
  const float* __restrict__ xa   = d1 ? xa1   : xa0;
  const float* __restrict__ sg1  = d1 ? s1_1  : s1_0;
  const float* __restrict__ sg2  = d1 ? s2_1  : s2_0;
  const float* __restrict__ wa   = d1 ? wa1   : wa0;
  const float* __restrict__ wg1  = d1 ? w1_1  : w1_0;
  const float* __restrict__ wg2  = d1 ? w2_1  : w2_0;
  const float* __restrict__ bias = d1 ? bias1 : bias0;
  const float* __restrict__ gin  = d1 ? gin1  : gin0;
  const float* __restrict__ cin  = d1 ? cin1  : cin0;
  float* __restrict__ cout = d1 ? cout1 : cout0;
  float* __restrict__ hout = d1 ? hout1 : hout0;
  __hip_bfloat16* __restrict__ hbf = d1 ? hbf1 : hbf0;

  const int tid  = threadIdx.x;
  const int lane = tid & 63;
  const int warp = tid >> 6;       // 0..15
  const int kc   = warp >> 2;      // K-chunk 0..3
  const int wh   = warp & 3;       // h-pair 0..3
  const int bid7 = blockIdx.x & 127;
  const int colbase = (bid7 & 1) << 6;
  const int hgrp = bid7 >> 1;
  const int hbase = __builtin_amdgcn_readfirstlane(hgrp * 8 + wh * 2);
  const int b = colbase + lane;

  float acc[2][4];
#pragma unroll
  for (int hh = 0; hh < 2; ++hh)
#pragma unroll
    for (int g = 0; g < 4; ++g) acc[hh][g] = 0.0f;

  if (kc == 0) {
#pragma unroll
    for (int hh = 0; hh < 2; ++hh)
#pragma unroll
      for (int g = 0; g < 4; ++g) {
        int n = g * 512 + hbase + hh;
        float v = bias[n];
        if (gin != nullptr) v += gin[(size_t)n * 128 + b];
        acc[hh][g] = v;
      }
    if constexpr (XLEN > 0) {
#pragma unroll
      for (int j = 0; j < XLEN; ++j) {
        float hv = xa[j * 128 + b];
#pragma unroll
        for (int hh = 0; hh < 2; ++hh)
#pragma unroll
          for (int g = 0; g < 4; ++g)
            acc[hh][g] = fmaf(hv, wa[(g * 512 + hbase + hh) * XLEN + j], acc[hh][g]);
      }
    }
  }

  if constexpr (!FIRST) {
#pragma unroll 1
    for (int seg = 0; seg < NSEG; ++seg) {
      const float* __restrict__ S = seg ? sg2 : sg1;
      const float* __restrict__ W = seg ? wg2 : wg1;
#pragma unroll 1
      for (int ph = 0; ph < 2; ++ph) {
        const int rbase = ph * 256;
        __syncthreads();   // previous phase/segment readers done
        // stage 256 rows x 64 cols (float4 per thread, 4 iters)
#pragma unroll
        for (int it = 0; it < 4; ++it) {
          int r  = it * 64 + (tid >> 4);
          int c4 = (tid & 15) * 4;
          float4 v = *(const float4*)&S[(size_t)(rbase + r) * 128 + colbase + c4];
          *(float4*)&xbuf[r * 64 + c4] = v;
        }
        __syncthreads();
        const float* __restrict__ Wr[2][4];
#pragma unroll
        for (int hh = 0; hh < 2; ++hh)
#pragma unroll
          for (int g = 0; g < 4; ++g)
            Wr[hh][g] = W + (size_t)(g * 512 + hbase + hh) * 512 + rbase + kc * 64;
        const int rb = kc * 64;
#pragma unroll 4
        for (int k = 0; k < 64; ++k) {
          float hv = xbuf[(rb + k) * 64 + lane];
#pragma unroll
          for (int hh = 0; hh < 2; ++hh)
#pragma unroll
            for (int g = 0; g < 4; ++g)
              acc[hh][g] = fmaf(hv, Wr[hh][g][k], acc[hh][g]);
        }
      }
    }
  }

  // cross-warp K reduction (red aliases xbuf)
  __syncthreads();
  if (kc != 0) {
    float* red = xbuf;
    int base = ((kc - 1) * 4 + wh) * 512;
#pragma unroll
    for (int hh = 0; hh < 2; ++hh)
#pragma unroll
      for (int g = 0; g < 4; ++g)
        red[base + (hh * 4 + g) * 64 + lane] = acc[hh][g];
  }
  __syncthreads();
  if (kc == 0) {
    const float* red = xbuf;
#pragma unroll
    for (int km = 0; km < 3; ++km)
#pragma unroll
      for (int hh = 0; hh < 2; ++hh)
#pragma unroll
        for (int g = 0; g < 4; ++g)
          acc[hh][g] += red[(km * 4 + wh) * 512 + (hh * 4 + g) * 64 + lane];
#pragma unroll
    for (int hh = 0; hh < 2; ++hh) {
      int h = hbase + hh;
      float cp = FIRST ? 0.0f : cin[h * 128 + b];
      float gi = acc[hh][0], gf = acc[hh][1], gg = acc[hh][2], go = acc[hh][3];
      float c  = sigm_(gf) * cp + sigm_(gi) * tanhf(gg);
      float hv = sigm_(go) * tanhf(c);
      cout[h * 128 + b] = c;
      hout[h * 128 + b] = hv;
      if constexpr (WBF) hbf[h * 128 + b] = __float2bfloat16(hv);
    }
  }
}

// ---------------------------------------------------------------------------
// bf16 MFMA window GEMM: winbuf[d][sl][n][b] = sum_k W_ih1[d][n][k]*ys1[t][k][b]
// t = d ? 511-(w32+sl) : w32+sl. M=2048(n), N=4096(sl*128+b), K=1024 per dir.
// Block 256 thr = 4 waves; wave tile 32(M)x64(N); no LDS (A 16B-contig global,
// B strided global, all L2/L3-resident). fp32 accum.
// Layouts (guide §3, m89/m91-verified C/D): A lane: row=l&15, k=(l>>4)*8+j;
// B lane: col=l&15, k=(l>>4)*8+j; D lane j: row=(l>>4)*4+j, col=l&15.
// ---------------------------------------------------------------------------
__global__ __launch_bounds__(256) void k_gih1(
    const __hip_bfloat16* __restrict__ wihb, const __hip_bfloat16* __restrict__ ys1b,
    float* __restrict__ winbuf, int w32)
{
  const int bx = blockIdx.x & 31;          // M tile (64 rows)
  const int by = (blockIdx.x >> 5) & 31;   // N tile (128 cols)
  const int d  = blockIdx.x >> 10;
  const int tid = threadIdx.x, lane = tid & 63, w = tid >> 6;
  const int wm = w >> 1, wn = w & 1;
  const int m0 = bx * 64 + wm * 32;
  const int n0 = by * 128 + wn * 64;
  const int r  = lane & 15, kb = lane >> 4;

  const short* A = (const short*)wihb + (size_t)d * 2048 * 1024;
  const short* B = (const short*)ys1b;

  f32x4 acc[2][4];
#pragma unroll
  for (int am = 0; am < 2; ++am)
#pragma unroll
    for (int bn = 0; bn < 4; ++bn) acc[am][bn] = (f32x4){0.f, 0.f, 0.f, 0.f};

  int tcol[4], bcol[4];
#pragma unroll
  for (int bn = 0; bn < 4; ++bn) {
    int col = n0 + bn * 16 + r;
    int sl  = col >> 7;
    tcol[bn] = d ? (511 - (w32 + sl)) : (w32 + sl);
    bcol[bn] = col & 127;
  }

#pragma unroll 1
  for (int kk = 0; kk < 1024; kk += 32) {
    short8 af[2];
#pragma unroll
    for (int am = 0; am < 2; ++am)
      af[am] = *(const short8*)&A[(size_t)(m0 + am * 16 + r) * 1024 + kk + kb * 8];
    short8 bf[4];
#pragma unroll
    for (int bn = 0; bn < 4; ++bn) {
      const short* p = B + (size_t)tcol[bn] * 131072 + (size_t)(kk + kb * 8) * 128 + bcol[bn];
#pragma unroll
      for (int j = 0; j < 8; ++j) bf[bn][j] = p[j * 128];
    }
#pragma unroll
    for (int am = 0; am < 2; ++am)
#pragma unroll
      for (int bn = 0; bn < 4; ++bn)
        acc[am][bn] = __builtin_amdgcn_mfma_f32_16x16x32_bf16(af[am], bf[bn], acc[am][bn], 0, 0, 0);
  }

#pragma unroll
  for (int am = 0; am < 2; ++am)
#pragma unroll
    for (int bn = 0; bn < 4; ++bn) {
      int col = n0 + bn * 16 + r;
      int sl  = col >> 7, bb = col & 127;
#pragma unroll
      for (int j = 0; j < 4; ++j) {
        int row = m0 + am * 16 + kb * 4 + j;
        winbuf[((size_t)(d * 32 + sl) * 2048 + row) * 128 + bb] = acc[am][bn][j];
      }
    }
}

// fp32 -> bf16 weight conversion
__global__ __launch_bounds__(256) void k_wcvt(
    const float* __restrict__ src, __hip_bfloat16* __restrict__ dst, int n)
{
  int i = blockIdx.x * 256 + threadIdx.x;
  if (i < n) dst[i] = __float2bfloat16(src[i]);
}

// Transpose X -> Xt [t][j][128]; build xdecT for decoder t=0.
__global__ __launch_bounds__(256) void k_pre(
    const float* __restrict__ X, const float* __restrict__ fut,
    float* __restrict__ Xt, float* __restrict__ xdecT)
{
  int t = blockIdx.x;
  int tid = threadIdx.x;
  for (int i = tid; i < 1024; i += 256) {
    int j = i >> 7, b = i & 127;
    Xt[(size_t)t * 1024 + j * 128 + b] = X[(size_t)b * 4096 + t * 8 + j];
  }
  if (t == 0 && tid < 128) {
    int b = tid;
    xdecT[b] = X[(size_t)b * 4096 + 511 * 8 + 0];
#pragma unroll
    for (int j = 0; j < 7; ++j)
      xdecT[(1 + j) * 128 + b] = fut[(size_t)b * 448 + j];
  }
}

// h_m / c_m = elu([hf0,hb0,hf1,hb1] @ w_bidi.T + b_bidi) -> decoder init states
__global__ __launch_bounds__(256) void k_mix(
    const float* __restrict__ h0f, const float* __restrict__ h0b,
    const float* __restrict__ h1f, const float* __restrict__ h1b,
    const float* __restrict__ c0f, const float* __restrict__ c0bb,
    const float* __restrict__ c1f, const float* __restrict__ c1bb,
    const float* __restrict__ w, const float* __restrict__ bias,
    float* __restrict__ h_dst, float* __restrict__ c_dst)
{
  int wgl  = blockIdx.x * 4 + (threadIdx.x >> 6);
  int lane = threadIdx.x & 63;
  int sel  = __builtin_amdgcn_readfirstlane(wgl >> 11);
  int rem  = wgl & 2047;
  int n    = __builtin_amdgcn_readfirstlane(rem >> 1);
  int half = rem & 1;
  int b    = (half << 6) + lane;
  const float* __restrict__ A0 = sel ? c0f  : h0f;
  const float* __restrict__ A1 = sel ? c0bb : h0b;
  const float* __restrict__ A2 = sel ? c1f  : h1f;
  const float* __restrict__ A3 = sel ? c1bb : h1b;
  const float* __restrict__ Wn = w + (size_t)n * 2048;
  float acc = bias[n];
#pragma unroll 8
  for (int k = 0; k < 512; ++k) acc = fmaf(A0[k * 128 + b], Wn[k], acc);
#pragma unroll 8
  for (int k = 0; k < 512; ++k) acc = fmaf(A1[k * 128 + b], Wn[512 + k], acc);
#pragma unroll 8
  for (int k = 0; k < 512; ++k) acc = fmaf(A2[k * 128 + b], Wn[1024 + k], acc);
#pragma unroll 8
  for (int k = 0; k < 512; ++k) acc = fmaf(A3[k * 128 + b], Wn[1536 + k], acc);
  float v = acc > 0.0f ? acc : (__expf(acc) - 1.0f);
  float* dst = sel ? c_dst : h_dst;
  dst[n * 128 + b] = v;
}

// y = h1 @ w_out.T + b_out -> out[:,t,:,:]; feed back y[:,0], fut[t+1] -> xdecT
__global__ __launch_bounds__(256) void k_dec_out(
    const float* __restrict__ h1, const float* __restrict__ w_out,
    const float* __restrict__ b_out, const float* __restrict__ fut,
    float* __restrict__ out, float* __restrict__ xdecT, int t)
{
  __shared__ float red[4][64];
  int bid = blockIdx.x;
  int tid = threadIdx.x;
  if (bid == 10) {
    if (tid < 128 && t + 1 < 64) {
      int b = tid;
#pragma unroll
      for (int j = 0; j < 7; ++j)
        xdecT[(1 + j) * 128 + b] = fut[(size_t)b * 448 + (t + 1) * 7 + j];
    }
    return;
  }
  int lane = tid & 63, warp = tid >> 6;
  int q    = __builtin_amdgcn_readfirstlane(bid >> 1);
  int half = bid & 1;
  int b    = half * 64 + lane;
  const float* __restrict__ Wq = w_out + q * 512 + warp * 128;
  const float* __restrict__ Hh = h1 + (size_t)warp * 128 * 128;
  float acc = 0.0f;
#pragma unroll 8
  for (int k = 0; k < 128; ++k) acc = fmaf(Hh[k * 128 + b], Wq[k], acc);
  red[warp][lane] = acc;
  __syncthreads();
  if (warp == 0) {
    float s = red[0][lane] + red[1][lane] + red[2][lane] + red[3][lane] + b_out[q];
    out[(size_t)b * 320 + t * 5 + q] = s;
    if (q == 0 && t + 1 < 64) xdecT[b] = s;
  }
}

extern "C" void kernel_launch(void* const* d_in, const int* in_sizes, int n_in,
                              void* d_out, int out_size, void* d_ws, size_t ws_size,
                              hipStream_t stream) {
  (void)in_sizes; (void)n_in; (void)out_size; (void)ws_size;
  const float* X      = (const float*)d_in[0];
  const float* fut    = (const float*)d_in[1];
  const float* e_wih0 = (const float*)d_in[4];
  const float* e_whh0 = (const float*)d_in[5];
  const float* e_b0   = (const float*)d_in[6];
  const float* e_wih1 = (const float*)d_in[7];
  const float* e_whh1 = (const float*)d_in[8];
  const float* e_b1   = (const float*)d_in[9];
  const float* d_wih0 = (const float*)d_in[10];
  const float* d_whh0 = (const float*)d_in[11];
  const float* d_b0   = (const float*)d_in[12];
  const float* d_wih1 = (const float*)d_in[13];
  const float* d_whh1 = (const float*)d_in[14];
  const float* d_b1   = (const float*)d_in[15];
  const float* w_bidi = (const float*)d_in[16];
  const float* b_bidi = (const float*)d_in[17];
  const float* w_out  = (const float*)d_in[18];
  const float* b_out  = (const float*)d_in[19];
  float* out = (float*)d_out;

  float* ws    = (float*)d_ws;
  float* Xt    = ws;                       // 524288
  float* h0s   = Xt + 524288;              // 262144
  float* h1T   = h0s + 262144;             // 262144
  float* c0buf = h1T + 262144;             // 131072
  float* c1buf = c0buf + 131072;           // 131072
  float* hdec  = c1buf + 131072;           // 262144
  float* cdec  = hdec + 262144;            // 131072
  float* xdecT = cdec + 131072;            // 1024
  float* winbuf = xdecT + 1024;            // 16777216
  __hip_bfloat16* wihb = (__hip_bfloat16*)(winbuf + 16777216);   // 4194304 bf16
  __hip_bfloat16* ys1b = (__hip_bfloat16*)((float*)(void*)wihb + 2097152); // 67108864 bf16

  k_pre<<<512, 256, 0, stream>>>(X, fut, Xt, xdecT);
  k_wcvt<<<16384, 256, 0, stream>>>(e_wih1, wihb, 4194304);

  // ---- encoder layer 0: XLEN=8 x-part + K=512 recurrence, both dirs ----
  for (int s = 0; s < 512; ++s) {
    int t = 511 - s;
    int pr = s & 1, pw = pr ^ 1;
    const float* xa0 = Xt + (size_t)s * 1024;
    const float* sg0 = h0s + (size_t)pr * 131072;
    float* ho0 = h0s + (size_t)pw * 131072;
    __hip_bfloat16* hb0 = ys1b + (size_t)s * 131072;
    const float* xa1 = Xt + (size_t)t * 1024;
    const float* sg1 = h0s + (size_t)pr * 131072 + 65536;
    float* ho1 = h0s + (size_t)pw * 131072 + 65536;
    __hip_bfloat16* hb1 = ys1b + (size_t)t * 131072 + 65536;
    const float* wa1 = e_wih0 + 2048 * 8;
    const float* wb1 = e_whh0 + (size_t)2048 * 512;
    if (s == 0)
      k_cellK<8, 1, true, true><<<256, 1024, 0, stream>>>(
          xa0, sg0, nullptr, e_wih0, e_whh0, nullptr, e_b0, nullptr,
          nullptr, c0buf, ho0, hb0,
          xa1, sg1, nullptr, wa1, wb1, nullptr, e_b0 + 2048, nullptr,
          nullptr, c0buf + 65536, ho1, hb1);
    else
      k_cellK<8, 1, false, true><<<256, 1024, 0, stream>>>(
          xa0, sg0, nullptr, e_wih0, e_whh0, nullptr, e_b0, nullptr,
          c0buf, c0buf, ho0, hb0,
          xa1, sg1, nullptr, wa1, wb1, nullptr, e_b0 + 2048, nullptr,
          c0buf + 65536, c0buf + 65536, ho1, hb1);
  }
  // final L0 states at parity 0 (s=511 -> pw=0)

  // ---- encoder layer 1: per 32-step window: MFMA input GEMM, then cells ----
  for (int w = 0; w < 16; ++w) {
    k_gih1<<<2048, 256, 0, stream>>>(wihb, ys1b, winbuf, w * 32);
    for (int sl = 0; sl < 32; ++sl) {
      int s = w * 32 + sl;
      int pr = s & 1, pw = pr ^ 1;
      const float* sg0 = h1T + (size_t)pr * 131072;
      float* ho0 = h1T + (size_t)pw * 131072;
      const float* gi0 = winbuf + (size_t)sl * 262144;
      const float* sg1 = h1T + (size_t)pr * 131072 + 65536;
      float* ho1 = h1T + (size_t)pw * 131072 + 65536;
      const float* gi1 = winbuf + (size_t)(32 + sl) * 262144;
      const float* wb1 = e_whh1 + (size_t)2048 * 512;
      if (s == 0)
        k_cellK<0, 1, true, false><<<256, 1024, 0, stream>>>(
            nullptr, sg0, nullptr, nullptr, e_whh1, nullptr, e_b1, gi0,
            nullptr, c1buf, ho0, nullptr,
            nullptr, sg1, nullptr, nullptr, wb1, nullptr, e_b1 + 2048, gi1,
            nullptr, c1buf + 65536, ho1, nullptr);
      else
        k_cellK<0, 1, false, false><<<256, 1024, 0, stream>>>(
            nullptr, sg0, nullptr, nullptr, e_whh1, nullptr, e_b1, gi0,
            c1buf, c1buf, ho0, nullptr,
            nullptr, sg1, nullptr, nullptr, wb1, nullptr, e_b1 + 2048, gi1,
            c1buf + 65536, c1buf + 65536, ho1, nullptr);
    }
  }
  // final L1 states at parity 0

  // ---- bidi-state mixing -> decoder initial states ----
  k_mix<<<1024, 256, 0, stream>>>(
      h0s + 0, h0s + 65536, h1T + 0, h1T + 65536,
      c0buf, c0buf + 65536, c1buf, c1buf + 65536,
      w_bidi, b_bidi, hdec, cdec);

  // ---- decoder: 64 autoregressive steps ----
  for (int t = 0; t < 64; ++t) {
    int pr = t & 1, pw = pr ^ 1;
    {
      const float* sg = hdec + (size_t)pr * 131072;
      float* ho = hdec + (size_t)pw * 131072;
      k_cellK<8, 1, false, false><<<128, 1024, 0, stream>>>(
          xdecT, sg, nullptr, d_wih0, d_whh0, nullptr, d_b0, nullptr,
          cdec, cdec, ho, nullptr,
          xdecT, sg, nullptr, d_wih0, d_whh0, nullptr, d_b0, nullptr,
          cdec, cdec, ho, nullptr);
    }
    {
      const float* s1 = hdec + (size_t)pw * 131072;            // h0 current
      const float* s2 = hdec + (size_t)pr * 131072 + 65536;    // h1 prev
      float* ho = hdec + (size_t)pw * 131072 + 65536;
      k_cellK<0, 2, false, false><<<128, 1024, 0, stream>>>(
          nullptr, s1, s2, nullptr, d_wih1, d_whh1, d_b1, nullptr,
          cdec + 65536, cdec + 65536, ho, nullptr,
          nullptr, s1, s2, nullptr, d_wih1, d_whh1, d_b1, nullptr,
          cdec + 65536, cdec + 65536, ho, nullptr);
    }
    k_dec_out<<<11, 256, 0, stream>>>(hdec + (size_t)pw * 131072 + 65536,
                                      w_out, b_out, fut, out, xdecT, t);
  }
}

// Round 5
// 30461.444 us; speedup vs baseline: 5.5813x; 1.4629x over previous
//
#include <hip/hip_runtime.h>
#include <hip/hip_bf16.h>
#include <cstddef>
#include <cstdint>

// ---------------------------------------------------------------------------
// RecurrentEncoderDecoder (B=128, T=512, H=512, HOR=64, M=1, Q=5, DFF=7)
// Round 5: all LSTM cell GEMMs -> bf16 MFMA (16x16x32), fp32 accum/c-path.
// Weights pre-packed once per call: rows interleaved p = h*4 + gate, K-concat
// [W_hh | W_ih | 0-pad]; h stored transposed bf16 hT[b][k] so B-frags are
// contiguous short8. ys1T doubles as L0 state and L1 input record.
//
// Workspace ~159 MiB (floats):
//   xpT    bf16 [512][128][32]        1,048,576 fs
//   ys1T   bf16 [512][128][1024]     33,554,432 fs
//   h1T    bf16 [2par][2dir][128][512]  131,072 fs
//   hdecT  bf16 [2par][2lay][128][512]  131,072 fs
//   xdecTb bf16 [128][32]                 2,048 fs
//   Apk*   bf16 packed weights        5,865,472 fs
//   bpk    f32  [6][2048]                12,288
//   hfin0/1 f32 [2dir][512][128]      2x131,072
//   c0/c1/cdec f32 [2][512][128]      3x131,072
//   hm_dst f32 [1024][128]              131,072
//   hdecF  f32 [512][128]                65,536
// ---------------------------------------------------------------------------

typedef __attribute__((ext_vector_type(8))) short short8;
typedef __attribute__((ext_vector_type(4))) float f32x4;

__device__ __forceinline__ float sigm_(float x) { return 1.0f / (1.0f + __expf(-x)); }

struct MProb {
  const __hip_bfloat16* A;    // packed bf16 [2048][KT], p = h*4+g
  const float* bpk;           // packed bias [2048]
  const __hip_bfloat16* S0;   // B seg0 [128][ld0] (prev h)
  const __hip_bfloat16* S1;   // B seg1 [128][ld1] (x / ys1 / h-other)
  const float* cin;           // [512][128]
  float* cout;                // [512][128]
  __hip_bfloat16* hT;         // out h, [128][ldh]
  float* hf32;                // optional fp32 h [512][128]
  int ld0, ld1, ldh;
};

// Grid: nprob*32 blocks x 256 thr (4 waves). Block = 64 packed rows x 128 b.
// Wave (wm,wn) = 32 rows x 64 cols; frags: 2 A x 4 B; D lane: col=l&15,
// row=(l>>4)*4+j -> j=0..3 are the 4 gates of one h (rows packed h*4+g).
template<int N0, int N1, int KT, bool FIRST, bool WF32>
__global__ __launch_bounds__(256) void k_mcell(MProb P0, MProb P1)
{
  const MProb P = (blockIdx.x >= 32) ? P1 : P0;
  const int m0  = (blockIdx.x & 31) * 64;
  const int tid = threadIdx.x;
  const int lane = tid & 63;
  const int w  = tid >> 6;
  const int wm = w >> 1, wn = w & 1;
  const int r = lane & 15, q = lane >> 4;

  f32x4 acc[2][4];
#pragma unroll
  for (int am = 0; am < 2; ++am)
#pragma unroll
    for (int bn = 0; bn < 4; ++bn) acc[am][bn] = (f32x4){0.f, 0.f, 0.f, 0.f};

  const short* Ab = (const short*)P.A + (size_t)(m0 + wm * 32 + r) * KT + q * 8;

  if constexpr (!FIRST) {
    const short* Bb = (const short*)P.S0 + (size_t)(wn * 64 + r) * P.ld0 + q * 8;
    const size_t bs = (size_t)16 * P.ld0;
#pragma unroll 4
    for (int kk = 0; kk < N0; ++kk) {
      short8 a0 = *(const short8*)(Ab + kk * 32);
      short8 a1 = *(const short8*)(Ab + (size_t)16 * KT + kk * 32);
      short8 b0 = *(const short8*)(Bb + kk * 32);
      short8 b1 = *(const short8*)(Bb + kk * 32 + bs);
      short8 b2 = *(const short8*)(Bb + kk * 32 + 2 * bs);
      short8 b3 = *(const short8*)(Bb + kk * 32 + 3 * bs);
      acc[0][0] = __builtin_amdgcn_mfma_f32_16x16x32_bf16(a0, b0, acc[0][0], 0, 0, 0);
      acc[0][1] = __builtin_amdgcn_mfma_f32_16x16x32_bf16(a0, b1, acc[0][1], 0, 0, 0);
      acc[0][2] = __builtin_amdgcn_mfma_f32_16x16x32_bf16(a0, b2, acc[0][2], 0, 0, 0);
      acc[0][3] = __builtin_amdgcn_mfma_f32_16x16x32_bf16(a0, b3, acc[0][3], 0, 0, 0);
      acc[1][0] = __builtin_amdgcn_mfma_f32_16x16x32_bf16(a1, b0, acc[1][0], 0, 0, 0);
      acc[1][1] = __builtin_amdgcn_mfma_f32_16x16x32_bf16(a1, b1, acc[1][1], 0, 0, 0);
      acc[1][2] = __builtin_amdgcn_mfma_f32_16x16x32_bf16(a1, b2, acc[1][2], 0, 0, 0);
      acc[1][3] = __builtin_amdgcn_mfma_f32_16x16x32_bf16(a1, b3, acc[1][3], 0, 0, 0);
    }
  }
  {
    const short* Bb = (const short*)P.S1 + (size_t)(wn * 64 + r) * P.ld1 + q * 8;
    const size_t bs = (size_t)16 * P.ld1;
#pragma unroll 4
    for (int kk = 0; kk < N1; ++kk) {
      short8 a0 = *(const short8*)(Ab + (size_t)(N0 + kk) * 32);
      short8 a1 = *(const short8*)(Ab + (size_t)16 * KT + (size_t)(N0 + kk) * 32);
      short8 b0 = *(const short8*)(Bb + kk * 32);
      short8 b1 = *(const short8*)(Bb + kk * 32 + bs);
      short8 b2 = *(const short8*)(Bb + kk * 32 + 2 * bs);
      short8 b3 = *(const short8*)(Bb + kk * 32 + 3 * bs);
      acc[0][0] = __builtin_amdgcn_mfma_f32_16x16x32_bf16(a0, b0, acc[0][0], 0, 0, 0);
      acc[0][1] = __builtin_amdgcn_mfma_f32_16x16x32_bf16(a0, b1, acc[0][1], 0, 0, 0);
      acc[0][2] = __builtin_amdgcn_mfma_f32_16x16x32_bf16(a0, b2, acc[0][2], 0, 0, 0);
      acc[0][3] = __builtin_amdgcn_mfma_f32_16x16x32_bf16(a0, b3, acc[0][3], 0, 0, 0);
      acc[1][0] = __builtin_amdgcn_mfma_f32_16x16x32_bf16(a1, b0, acc[1][0], 0, 0, 0);
      acc[1][1] = __builtin_amdgcn_mfma_f32_16x16x32_bf16(a1, b1, acc[1][1], 0, 0, 0);
      acc[1][2] = __builtin_amdgcn_mfma_f32_16x16x32_bf16(a1, b2, acc[1][2], 0, 0, 0);
      acc[1][3] = __builtin_amdgcn_mfma_f32_16x16x32_bf16(a1, b3, acc[1][3], 0, 0, 0);
    }
  }

  // epilogue: per (am,bn,lane) one (h, b) cell; regs j=0..3 = i,f,g,o gates
#pragma unroll
  for (int am = 0; am < 2; ++am) {
    const int pb = m0 + wm * 32 + am * 16 + q * 4;
    const int h  = pb >> 2;
    const float4 bb = *(const float4*)&P.bpk[pb];
#pragma unroll
    for (int bn = 0; bn < 4; ++bn) {
      const int col = wn * 64 + bn * 16 + r;
      float gi = acc[am][bn][0] + bb.x;
      float gf = acc[am][bn][1] + bb.y;
      float gg = acc[am][bn][2] + bb.z;
      float go = acc[am][bn][3] + bb.w;
      float cp = 0.0f;
      if constexpr (!FIRST) cp = P.cin[h * 128 + col];
      float c  = sigm_(gf) * cp + sigm_(gi) * tanhf(gg);
      float hv = sigm_(go) * tanhf(c);
      P.cout[h * 128 + col] = c;
      P.hT[(size_t)col * P.ldh + h] = __float2bfloat16(hv);
      if constexpr (WF32) P.hf32[h * 128 + col] = hv;
    }
  }
}

// Pack weights: dst[p][kc], p=h*4+g; kc<512 from Whh, 512<=kc<512+XW from Wih,
// else 0. grid = dim3(ceil(KT/256), 2048).
__global__ __launch_bounds__(256) void k_wpack(
    const float* __restrict__ Whh, const float* __restrict__ Wih,
    int XW, int KT, __hip_bfloat16* __restrict__ dst)
{
  int kc = blockIdx.x * 256 + threadIdx.x;
  int p  = blockIdx.y;
  if (kc >= KT) return;
  int h = p >> 2, g = p & 3;
  int row = g * 512 + h;
  float v;
  if (kc < 512)            v = Whh[(size_t)row * 512 + kc];
  else if (kc - 512 < XW)  v = Wih[(size_t)row * XW + (kc - 512)];
  else                     v = 0.0f;
  dst[(size_t)p * KT + kc] = __float2bfloat16(v);
}

// Pack 6 bias sets into p = h*4+g order. grid 48 x 256.
__global__ __launch_bounds__(256) void k_bpack(
    const float* b0, const float* b1, const float* b2,
    const float* b3, const float* b4, const float* b5, float* bpk)
{
  int i = blockIdx.x * 256 + threadIdx.x;
  if (i >= 6 * 2048) return;
  int set = i >> 11, p = i & 2047;
  const float* src = set == 0 ? b0 : set == 1 ? b1 : set == 2 ? b2
                   : set == 3 ? b3 : set == 4 ? b4 : b5;
  bpk[i] = src[(p & 3) * 512 + (p >> 2)];
}

// X -> xpT bf16 [t][b][32] (j<8 real, rest 0); init xdecTb at t=0.
__global__ __launch_bounds__(256) void k_pre(
    const float* __restrict__ X, const float* __restrict__ fut,
    __hip_bfloat16* __restrict__ xpT, __hip_bfloat16* __restrict__ xdecTb)
{
  int t = blockIdx.x, tid = threadIdx.x;
  for (int i = tid; i < 4096; i += 256) {
    int b = i >> 5, j = i & 31;
    float v = (j < 8) ? X[(size_t)b * 4096 + t * 8 + j] : 0.0f;
    xpT[(size_t)t * 4096 + i] = __float2bfloat16(v);
  }
  if (t == 0 && tid < 128) {
    int b = tid;
    xdecTb[b * 32 + 0] = __float2bfloat16(X[(size_t)b * 4096 + 511 * 8 + 0]);
#pragma unroll
    for (int j = 0; j < 7; ++j)
      xdecTb[b * 32 + 1 + j] = __float2bfloat16(fut[(size_t)b * 448 + j]);
    for (int j = 8; j < 32; ++j) xdecTb[b * 32 + j] = __float2bfloat16(0.0f);
  }
}

// h_m / c_m = elu([hf0,hb0,hf1,hb1] @ w_bidi.T + b_bidi). grid 1024 x 256.
__global__ __launch_bounds__(256) void k_mix(
    const float* __restrict__ h0f, const float* __restrict__ h0b,
    const float* __restrict__ h1f, const float* __restrict__ h1b,
    const float* __restrict__ c0f, const float* __restrict__ c0bb,
    const float* __restrict__ c1f, const float* __restrict__ c1bb,
    const float* __restrict__ w, const float* __restrict__ bias,
    float* __restrict__ h_dst, float* __restrict__ c_dst)
{
  int wgl  = blockIdx.x * 4 + (threadIdx.x >> 6);
  int lane = threadIdx.x & 63;
  int sel  = __builtin_amdgcn_readfirstlane(wgl >> 11);
  int rem  = wgl & 2047;
  int n    = __builtin_amdgcn_readfirstlane(rem >> 1);
  int half = rem & 1;
  int b    = (half << 6) + lane;
  const float* __restrict__ A0 = sel ? c0f  : h0f;
  const float* __restrict__ A1 = sel ? c0bb : h0b;
  const float* __restrict__ A2 = sel ? c1f  : h1f;
  const float* __restrict__ A3 = sel ? c1bb : h1b;
  const float* __restrict__ Wn = w + (size_t)n * 2048;
  float acc = bias[n];
#pragma unroll 8
  for (int k = 0; k < 512; ++k) acc = fmaf(A0[k * 128 + b], Wn[k], acc);
#pragma unroll 8
  for (int k = 0; k < 512; ++k) acc = fmaf(A1[k * 128 + b], Wn[512 + k], acc);
#pragma unroll 8
  for (int k = 0; k < 512; ++k) acc = fmaf(A2[k * 128 + b], Wn[1024 + k], acc);
#pragma unroll 8
  for (int k = 0; k < 512; ++k) acc = fmaf(A3[k * 128 + b], Wn[1536 + k], acc);
  float v = acc > 0.0f ? acc : (__expf(acc) - 1.0f);
  float* dst = sel ? c_dst : h_dst;
  dst[n * 128 + b] = v;
}

// hm_dst fp32 [1024][128] -> hdecT par0 bf16 [layer][128][512]
__global__ __launch_bounds__(256) void k_t2b(
    const float* __restrict__ hm, __hip_bfloat16* __restrict__ hdecT0)
{
  int i = blockIdx.x * 256 + threadIdx.x;
  if (i >= 131072) return;
  int n = i >> 7, b = i & 127;
  hdecT0[(size_t)(n >> 9) * 65536 + b * 512 + (n & 511)] = __float2bfloat16(hm[i]);
}

// y = h1 @ w_out.T + b_out -> out; feed back y[:,0] (bf16) + fut[t+1] -> xdecTb
__global__ __launch_bounds__(256) void k_dec_out(
    const float* __restrict__ h1, const float* __restrict__ w_out,
    const float* __restrict__ b_out, const float* __restrict__ fut,
    float* __restrict__ out, __hip_bfloat16* __restrict__ xdecTb, int t)
{
  __shared__ float red[4][64];
  int bid = blockIdx.x;
  int tid = threadIdx.x;
  if (bid == 10) {
    if (tid < 128 && t + 1 < 64) {
      int b = tid;
#pragma unroll
      for (int j = 0; j < 7; ++j)
        xdecTb[b * 32 + 1 + j] = __float2bfloat16(fut[(size_t)b * 448 + (t + 1) * 7 + j]);
    }
    return;
  }
  int lane = tid & 63, warp = tid >> 6;
  int q    = __builtin_amdgcn_readfirstlane(bid >> 1);
  int half = bid & 1;
  int b    = half * 64 + lane;
  const float* __restrict__ Wq = w_out + q * 512 + warp * 128;
  const float* __restrict__ Hh = h1 + (size_t)warp * 128 * 128;
  float acc = 0.0f;
#pragma unroll 8
  for (int k = 0; k < 128; ++k) acc = fmaf(Hh[k * 128 + b], Wq[k], acc);
  red[warp][lane] = acc;
  __syncthreads();
  if (warp == 0) {
    float s = red[0][lane] + red[1][lane] + red[2][lane] + red[3][lane] + b_out[q];
    out[(size_t)b * 320 + t * 5 + q] = s;
    if (q == 0 && t + 1 < 64) xdecTb[b * 32] = __float2bfloat16(s);
  }
}

extern "C" void kernel_launch(void* const* d_in, const int* in_sizes, int n_in,
                              void* d_out, int out_size, void* d_ws, size_t ws_size,
                              hipStream_t stream) {
  (void)in_sizes; (void)n_in; (void)out_size; (void)ws_size;
  const float* X      = (const float*)d_in[0];
  const float* fut    = (const float*)d_in[1];
  const float* e_wih0 = (const float*)d_in[4];
  const float* e_whh0 = (const float*)d_in[5];
  const float* e_b0   = (const float*)d_in[6];
  const float* e_wih1 = (const float*)d_in[7];
  const float* e_whh1 = (const float*)d_in[8];
  const float* e_b1   = (const float*)d_in[9];
  const float* d_wih0 = (const float*)d_in[10];
  const float* d_whh0 = (const float*)d_in[11];
  const float* d_b0   = (const float*)d_in[12];
  const float* d_wih1 = (const float*)d_in[13];
  const float* d_whh1 = (const float*)d_in[14];
  const float* d_b1   = (const float*)d_in[15];
  const float* w_bidi = (const float*)d_in[16];
  const float* b_bidi = (const float*)d_in[17];
  const float* w_out  = (const float*)d_in[18];
  const float* b_out  = (const float*)d_in[19];
  float* out = (float*)d_out;

  float* ws = (float*)d_ws;
  __hip_bfloat16* xpT    = (__hip_bfloat16*)(ws + 0);           // 1,048,576 fs
  __hip_bfloat16* ys1T   = (__hip_bfloat16*)(ws + 1048576);     // 33,554,432 fs
  __hip_bfloat16* h1T    = (__hip_bfloat16*)(ws + 34603008);    // 131,072 fs
  __hip_bfloat16* hdecT  = (__hip_bfloat16*)(ws + 34734080);    // 131,072 fs
  __hip_bfloat16* xdecTb = (__hip_bfloat16*)(ws + 34865152);    // 2,048 fs
  __hip_bfloat16* ApkL0  = (__hip_bfloat16*)(ws + 34867200);    // 1,114,112 fs
  __hip_bfloat16* ApkL1  = (__hip_bfloat16*)(ws + 35981312);    // 3,145,728 fs
  __hip_bfloat16* ApkD0  = (__hip_bfloat16*)(ws + 39127040);    // 557,056 fs
  __hip_bfloat16* ApkD1  = (__hip_bfloat16*)(ws + 39684096);    // 1,048,576 fs
  float* bpk   = ws + 40732672;    // 12,288
  float* hfin0 = ws + 40744960;    // 131,072
  float* hfin1 = ws + 40876032;    // 131,072
  float* c0buf = ws + 41007104;    // 131,072
  float* c1buf = ws + 41138176;    // 131,072
  float* cdec  = ws + 41269248;    // 131,072
  float* hmds  = ws + 41400320;    // 131,072
  float* hdecF = ws + 41531392;    // 65,536

  k_pre<<<512, 256, 0, stream>>>(X, fut, xpT, xdecTb);
  k_wpack<<<dim3(3, 2048), 256, 0, stream>>>(e_whh0, e_wih0, 8, 544, ApkL0);
  k_wpack<<<dim3(3, 2048), 256, 0, stream>>>(e_whh0 + (size_t)2048 * 512,
                                             e_wih0 + 2048 * 8, 8, 544,
                                             ApkL0 + (size_t)2048 * 544);
  k_wpack<<<dim3(6, 2048), 256, 0, stream>>>(e_whh1, e_wih1, 1024, 1536, ApkL1);
  k_wpack<<<dim3(6, 2048), 256, 0, stream>>>(e_whh1 + (size_t)2048 * 512,
                                             e_wih1 + (size_t)2048 * 1024, 1024, 1536,
                                             ApkL1 + (size_t)2048 * 1536);
  k_wpack<<<dim3(3, 2048), 256, 0, stream>>>(d_whh0, d_wih0, 8, 544, ApkD0);
  k_wpack<<<dim3(4, 2048), 256, 0, stream>>>(d_wih1, d_whh1, 512, 1024, ApkD1);
  k_bpack<<<48, 256, 0, stream>>>(e_b0, e_b0 + 2048, e_b1, e_b1 + 2048,
                                  d_b0, d_b1, bpk);

  // ---- encoder layer 0: K = 512 (hprev, via ys1T) + 32 (x) ----
  for (int s = 0; s < 512; ++s) {
    int t = 511 - s;
    MProb P0{ApkL0, bpk, ys1T + (size_t)(s > 0 ? s - 1 : 0) * 131072,
             xpT + (size_t)s * 4096, c0buf, c0buf,
             ys1T + (size_t)s * 131072, hfin0, 1024, 32, 1024};
    MProb P1{ApkL0 + (size_t)2048 * 544, bpk + 2048,
             ys1T + (size_t)(512 - s) * 131072 + 512,
             xpT + (size_t)t * 4096, c0buf + 65536, c0buf + 65536,
             ys1T + (size_t)t * 131072 + 512, hfin0 + 65536, 1024, 32, 1024};
    if (s == 0) k_mcell<16, 1, 544, true,  true><<<64, 256, 0, stream>>>(P0, P1);
    else        k_mcell<16, 1, 544, false, true><<<64, 256, 0, stream>>>(P0, P1);
  }

  // ---- encoder layer 1: K = 512 (hprev) + 1024 (ys1[t]) ----
  for (int s = 0; s < 512; ++s) {
    int t = 511 - s;
    int pr = s & 1, pw = pr ^ 1;
    MProb P0{ApkL1, bpk + 2 * 2048, h1T + (size_t)pr * 131072,
             ys1T + (size_t)s * 131072, c1buf, c1buf,
             h1T + (size_t)pw * 131072, hfin1, 512, 1024, 512};
    MProb P1{ApkL1 + (size_t)2048 * 1536, bpk + 3 * 2048,
             h1T + (size_t)pr * 131072 + 65536,
             ys1T + (size_t)t * 131072, c1buf + 65536, c1buf + 65536,
             h1T + (size_t)pw * 131072 + 65536, hfin1 + 65536, 512, 1024, 512};
    if (s == 0) k_mcell<16, 32, 1536, true,  true><<<64, 256, 0, stream>>>(P0, P1);
    else        k_mcell<16, 32, 1536, false, true><<<64, 256, 0, stream>>>(P0, P1);
  }

  // ---- bidi-state mixing -> decoder initial states ----
  k_mix<<<1024, 256, 0, stream>>>(
      hfin0, hfin0 + 65536, hfin1, hfin1 + 65536,
      c0buf, c0buf + 65536, c1buf, c1buf + 65536,
      w_bidi, b_bidi, hmds, cdec);
  k_t2b<<<512, 256, 0, stream>>>(hmds, hdecT);

  // ---- decoder: 64 autoregressive steps ----
  for (int t = 0; t < 64; ++t) {
    int pr = t & 1, pw = pr ^ 1;
    {
      MProb P0{ApkD0, bpk + 4 * 2048, hdecT + (size_t)pr * 131072,
               xdecTb, cdec, cdec,
               hdecT + (size_t)pw * 131072, nullptr, 512, 32, 512};
      k_mcell<16, 1, 544, false, false><<<32, 256, 0, stream>>>(P0, P0);
    }
    {
      MProb P0{ApkD1, bpk + 5 * 2048, hdecT + (size_t)pw * 131072,
               hdecT + (size_t)pr * 131072 + 65536, cdec + 65536, cdec + 65536,
               hdecT + (size_t)pw * 131072 + 65536, hdecF, 512, 512, 512};
      k_mcell<16, 16, 1024, false, true><<<32, 256, 0, stream>>>(P0, P0);
    }
    k_dec_out<<<11, 256, 0, stream>>>(hdecF, w_out, b_out, fut, out, xdecTb, t);
  }
}